// Round 1
// baseline (4615.190 us; speedup 1.0000x reference)
//
#include <hip/hip_runtime.h>

#define SEG_D 64

// One thread per float4 slot: 16 threads cover one row of 64 floats.
// Coalesced dwordx4 loads; HW fp32 atomics into the (cache-resident) output.
__global__ void __launch_bounds__(256) seg_accum_kernel(
    const float4* __restrict__ data4,
    const int* __restrict__ ids,
    float* __restrict__ out,
    float* __restrict__ counts,
    int n_slots)  // = N * 16
{
    int stride = gridDim.x * blockDim.x;
    for (int s = blockIdx.x * blockDim.x + threadIdx.x; s < n_slots; s += stride) {
        int row = s >> 4;
        int c4  = s & 15;
        int seg = ids[row];
        float4 v = data4[s];
        float* dst = out + (seg * SEG_D + c4 * 4);
        unsafeAtomicAdd(dst + 0, v.x);
        unsafeAtomicAdd(dst + 1, v.y);
        unsafeAtomicAdd(dst + 2, v.z);
        unsafeAtomicAdd(dst + 3, v.w);
        if (c4 == 0) unsafeAtomicAdd(counts + seg, 1.0f);
    }
}

// out[i] /= counts[i / 64], vectorized as float4 (16 float4 per segment row).
__global__ void __launch_bounds__(256) seg_div_kernel(
    float4* __restrict__ out4,
    const float* __restrict__ counts,
    int n4)  // = S * 16
{
    int stride = gridDim.x * blockDim.x;
    for (int i = blockIdx.x * blockDim.x + threadIdx.x; i < n4; i += stride) {
        float c = counts[i >> 4];
        float inv = 1.0f / c;
        float4 v = out4[i];
        v.x *= inv; v.y *= inv; v.z *= inv; v.w *= inv;
        out4[i] = v;
    }
}

extern "C" void kernel_launch(void* const* d_in, const int* in_sizes, int n_in,
                              void* d_out, int out_size, void* d_ws, size_t ws_size,
                              hipStream_t stream) {
    const float* data = (const float*)d_in[0];
    const int*   ids  = (const int*)d_in[1];
    // d_in[2] = num_segments scalar; we derive S from out_size instead.

    const int N = in_sizes[1];           // 4,000,000 rows
    const int S = out_size / SEG_D;      // 100,000 segments

    float* out    = (float*)d_out;
    float* counts = (float*)d_ws;        // S floats of scratch

    // Harness poisons d_out/d_ws to 0xAA before every timed call — zero them.
    hipMemsetAsync(d_out, 0, (size_t)out_size * sizeof(float), stream);
    hipMemsetAsync(d_ws, 0, (size_t)S * sizeof(float), stream);

    const int n_slots = N * 16;          // float4 slots
    const int block = 256;
    const int grid_accum = 8192;         // grid-stride; ~32 slots/thread
    seg_accum_kernel<<<grid_accum, block, 0, stream>>>(
        (const float4*)data, ids, out, counts, n_slots);

    const int n4 = S * 16;
    const int grid_div = (n4 + block - 1) / block;
    seg_div_kernel<<<grid_div, block, 0, stream>>>(
        (float4*)out, counts, n4);
}